// Round 17
// baseline (7248.155 us; speedup 1.0000x reference)
//
#include <hip/hip_runtime.h>
#include <cstdint>

typedef __attribute__((ext_vector_type(8))) short bf16x8;
typedef __attribute__((ext_vector_type(4))) float f32x4;
typedef unsigned short u16;
typedef unsigned int u32;

// ---- problem sizes ----
// B=4096, Nh=128, vox=64 (4x4x4), Kx=1024
// ---- ws layout (bytes), all 16B aligned ----
static const size_t OFF_WT = 0;          // bf16 [3][27][128 oc][128 ic] = 2,654,208
static const size_t OFF_XB = 2654464;    // bf16 [4096][1024]            = 8,388,608
static const size_t OFF_LB = 11043072;   // bf16 [3][8192 (oc*64+vo)][1024] = 50,331,648
static const size_t OFF_HT = 61374720;   // bf16 [4096][64 vox][128 ic]  = 67,108,864
static const size_t OFF_RH = 128483584;  // bf16 [4096][64 vox][128 ic]  = 67,108,864
// total = 195,592,448 bytes required in d_ws

__device__ __forceinline__ u16 f2bf(float x) {
  union { float f; u32 u; } v; v.f = x;
  u32 r = (v.u + 0x7FFFu + ((v.u >> 16) & 1u)) >> 16;
  return (u16)r;
}
__device__ __forceinline__ float bf2f(u16 x) {
  union { u32 u; float f; } v; v.u = ((u32)x) << 16; return v.f;
}

__device__ __forceinline__ void gload16(const void* g, void* l) {
  __builtin_amdgcn_global_load_lds(
      (const __attribute__((address_space(1))) uint32_t*)g,
      (__attribute__((address_space(3))) uint32_t*)l, 16, 0, 0);
}

// ---------------- conversions: W->wt (transposed), x->xb, L->Lb ----------------
__global__ __launch_bounds__(256) void k_cvt(
    const float* __restrict__ x,
    const float* __restrict__ Wz, const float* __restrict__ Wr, const float* __restrict__ Wm,
    const float* __restrict__ Lz, const float* __restrict__ Lr, const float* __restrict__ Lm,
    uint8_t* __restrict__ ws) {
  u16* wt = (u16*)(ws + OFF_WT);
  u16* xb = (u16*)(ws + OFF_XB);
  u16* lb = (u16*)(ws + OFF_LB);
  const long NWT = 3L * 27 * 128 * 128;   // 1,327,104
  const long NX  = 4096L * 1024;          // 4,194,304
  const long NL  = 3L * 8192 * 1024;      // 25,165,824
  const long total = NWT + NX + NL;
  for (long i = (long)blockIdx.x * blockDim.x + threadIdx.x; i < total;
       i += (long)gridDim.x * blockDim.x) {
    if (i < NWT) {
      long g = i / (27L * 16384);
      long r = i % (27L * 16384);
      long t = r / 16384;
      long oc = (r / 128) % 128;
      long ic = r % 128;
      const float* W = (g == 0) ? Wz : ((g == 1) ? Wr : Wm);
      wt[i] = f2bf(W[(oc * 128 + ic) * 27 + t]);
    } else if (i < NWT + NX) {
      long j = i - NWT;
      xb[j] = f2bf(x[j]);
    } else {
      long j = i - NWT - NX;
      long g = j / (8192L * 1024);
      long r = j % (8192L * 1024);
      const float* L = (g == 0) ? Lz : ((g == 1) ? Lr : Lm);
      lb[j] = f2bf(L[r]);
    }
  }
}

// ---------------- h [b][ic][vox] fp32 -> ht [b][vox][ic] bf16 ----------------
__global__ __launch_bounds__(256) void k_ht(const float* __restrict__ h, uint8_t* __restrict__ ws) {
  __shared__ float tile[128 * 65];
  int b = blockIdx.x;
  const float* hb = h + (size_t)b * 8192;
  u16* ht = (u16*)(ws + OFF_HT) + (size_t)b * 8192;
  for (int i = threadIdx.x; i < 8192; i += 256) {
    int ic = i >> 6, vo = i & 63;
    tile[ic * 65 + vo] = hb[i];
  }
  __syncthreads();
  for (int i = threadIdx.x; i < 8192; i += 256) {
    int vo = i >> 7, ic = i & 127;
    ht[i] = f2bf(tile[ic * 65 + vo]);
  }
}

// ---------------- fused z+r GEMM: tile M=128(batch) x N=256(z 0..127 | r 128..255) ----
// 8 waves (2M x 4N) each 64x64, 512 thr, BK=64. R14 frags-first single-buffer
// schedule: per panel, ds_read ALL frags into regs -> __syncthreads -> stage
// panel p+1 into the SAME 48KB buffer (A 16KB + B 32KB; safe: panel p is in
// regs) -> 32 MFMA -> __syncthreads (drains vmcnt). 48KB -> 3 blocks/CU =
// 24 waves/CU. Per-wave regs = R14's 144 (acc 64 + frags 64 + addr); (512,6)
// cap ~341 is non-binding -> no spill (R15/R16 lesson).
// A (ht/xb) staged ONCE for both gates: staged bytes -25% vs unfused.
// Staging: global_load_lds width=16, linear LDS dest, XOR-swizzle on the
// per-lane GLOBAL source chunk; reads use tile[row][c^(row&7)].
// Addressing identical to R11's refcheck-passed kernel (LB gate stride
// 16,777,216 B). Grid: XCD-chunked bijective swizzle, vo fast, mb slow.
__global__ __launch_bounds__(512, 6) void k_zr_gemm(
    uint8_t* __restrict__ ws,
    const float* __restrict__ bz, const float* __restrict__ br,
    u32* __restrict__ dout) {
  int bx = blockIdx.x;
  int L = (bx & 7) * 256 + (bx >> 3);   // nwg=2048, XCD-chunked
  int vo = L & 63, mb = L >> 6;

  const uint8_t* wt_b = ws + OFF_WT;          // [g][27][128][128] bf16
  const uint8_t* xb_b = ws + OFF_XB;
  const uint8_t* lb_b = ws + OFF_LB;          // [g][oc*64+vo][1024] bf16
  const uint8_t* ht_b = ws + OFF_HT;

  // LDS: [0,16K) A (128 rows x 128B); [16K,48K) B (256 rows x 128B) — single buffer
  __shared__ __align__(1024) uint8_t lds[49152];

  const int tid = threadIdx.x;
  const int w = tid >> 6;          // wave 0..7
  const int l = tid & 63;
  const int lrow = l >> 3;         // 0..7
  const int co = (((l & 7) ^ lrow) << 4);  // swizzled chunk byte offset (row&7 == lrow for all staged rows)
  const int wm = (w >> 2) * 64;    // 0 / 64
  const int wn = (w & 3) * 64;     // 0,64,128,192
  const int gw = w >> 2;           // B-staging gate for this wave
  const int lr16 = l & 15;
  const int lk = l >> 4;

  f32x4 acc[4][4];
#pragma unroll
  for (int m = 0; m < 4; ++m)
#pragma unroll
    for (int n = 0; n < 4; ++n) acc[m][n] = (f32x4){0.f, 0.f, 0.f, 0.f};

  // per-lane invariant source bases
  // A (2 loads: rows w*16 + i*8 + lrow)
  const uint8_t* aA_x = xb_b + ((size_t)(mb * 128 + w * 16 + lrow)) * 2048 + co;    // + kt*128 + i*16384
  const uint8_t* aA_t = ht_b + ((size_t)(mb * 128 + w * 16 + lrow)) * 16384 + co;   // + vi*256 + ih*128 + i*131072
  // B (4 loads: gate gw, oc = (w&3)*32 + j*8 + lrow); gate stride 16,777,216 B
  const uint8_t* aB_x = lb_b + (size_t)gw * 16777216 +
                        ((size_t)((w & 3) * 32 + lrow)) * 131072 + (size_t)vo * 2048 + co;  // + kt*128 + j*1048576
  const uint8_t* aB_t = wt_b + (size_t)gw * 884736 +
                        ((size_t)((w & 3) * 32 + lrow)) * 256 + co;                 // + t*32768 + ih*128 + j*2048

  const int d = vo >> 4, e = (vo >> 2) & 3, f = vo & 3;
  auto validT = [&](int t) {
    int p3 = t / 9 - 1, q3 = (t / 3) % 3 - 1, s3 = t % 3 - 1;
    int dd = d + p3, ee = e + q3, ff = f + s3;
    return dd >= 0 && dd <= 3 && ee >= 0 && ee <= 3 && ff >= 0 && ff <= 3;
  };
  const int nd = 3 - (d == 0) - (d == 3);
  const int ne = 3 - (e == 0) - (e == 3);
  const int nf = 3 - (f == 0) - (f == 3);
  const int NP = 16 + 2 * nd * ne * nf;

  int s_kt = 0;            // next projection panel
  int s_t = 0, s_ih = 0;   // next tap panel
  while (!validT(s_t)) ++s_t;

  auto stage_next = [&]() {
    uint8_t* Ad = lds + w * 2048;           // 2 loads x 1KB
    uint8_t* Bd = lds + 16384 + w * 4096;   // 4 loads x 1KB
    if (s_kt < 16) {
      int kt = s_kt;
#pragma unroll
      for (int i = 0; i < 2; ++i)
        gload16(aA_x + (size_t)kt * 128 + (size_t)i * 16384, Ad + i * 1024);
#pragma unroll
      for (int j = 0; j < 4; ++j)
        gload16(aB_x + (size_t)kt * 128 + (size_t)j * 1048576, Bd + j * 1024);
      ++s_kt;
    } else {
      int t = s_t, ih = s_ih;
      int dd = d + t / 9 - 1, ee = e + (t / 3) % 3 - 1, ff = f + t % 3 - 1;
      int vi = dd * 16 + ee * 4 + ff;
#pragma unroll
      for (int i = 0; i < 2; ++i)
        gload16(aA_t + (size_t)vi * 256 + ih * 128 + (size_t)i * 131072, Ad + i * 1024);
#pragma unroll
      for (int j = 0; j < 4; ++j)
        gload16(aB_t + (size_t)t * 32768 + ih * 128 + (size_t)j * 2048, Bd + j * 1024);
      s_ih ^= 1;
      if (!s_ih) { do { ++s_t; } while (s_t < 27 && !validT(s_t)); }
    }
  };

  // prologue: stage panel 0, drain
  stage_next();
  __syncthreads();
  for (int p = 0; p < NP; ++p) {
    const u16* At = (const u16*)lds;                 // 128 rows x 64
    const u16* Bt = (const u16*)(lds + 16384);       // 256 rows x 64
    // ---- read ALL fragments into registers first ----
    bf16x8 af[4][2], bfr[4][2];
#pragma unroll
    for (int m = 0; m < 4; ++m)
#pragma unroll
      for (int ks = 0; ks < 2; ++ks) {
        int row = wm + m * 16 + lr16;
        int c = ks * 4 + lk;
        af[m][ks] = *(const bf16x8*)&At[row * 64 + ((c ^ (row & 7)) * 8)];
      }
#pragma unroll
    for (int n = 0; n < 4; ++n)
#pragma unroll
      for (int ks = 0; ks < 2; ++ks) {
        int row = wn + n * 16 + lr16;
        int c = ks * 4 + lk;
        bfr[n][ks] = *(const bf16x8*)&Bt[row * 64 + ((c ^ (row & 7)) * 8)];
      }
    __syncthreads();   // all waves consumed panel p from LDS (buffer free)
    if (p + 1 < NP) stage_next();   // loads fly under the MFMAs
    // ---- MFMA on registers ----
#pragma unroll
    for (int ks = 0; ks < 2; ++ks)
#pragma unroll
      for (int m = 0; m < 4; ++m)
#pragma unroll
        for (int n = 0; n < 4; ++n)
          acc[m][n] = __builtin_amdgcn_mfma_f32_16x16x32_bf16(af[m][ks], bfr[n][ks], acc[m][n], 0, 0, 0);
    __syncthreads();   // drains vmcnt -> panel p+1 resident before next reads
  }

  // --- epilogue: waves with wn<128 produce z, wn>=128 produce r*h ---
  const int gate = wn >> 7;               // 0 = z, 1 = r
  const int ocb = wn & 127;
  const float* bias = gate ? br : bz;
  const u16* htp = (const u16*)(ws + OFF_HT);
  u16* rhp = (u16*)(ws + OFF_RH);
#pragma unroll
  for (int n = 0; n < 4; ++n) {
    int oc = ocb + n * 16 + lr16;
    float bv = bias[oc * 64 + vo];
#pragma unroll
    for (int m = 0; m < 4; ++m) {
#pragma unroll
      for (int j = 0; j < 4; ++j) {
        int brow = mb * 128 + wm + m * 16 + lk * 4 + j;  // batch index
        size_t pidx = (size_t)brow * 8192 + (size_t)vo * 128 + oc;
        float pre = acc[m][n][j] + bv;
        pre = fminf(fmaxf(pre, -30.f), 30.f);
        float sg = 1.f / (1.f + __expf(-pre));
        if (gate == 0) {
          dout[pidx] = (u32)f2bf(sg);           // z in lo16 (hi cleared)
        } else {
          float hv = bf2f(htp[pidx]);
          rhp[pidx] = f2bf(sg * hv);            // r * h
        }
      }
    }
  }
}

// ---------------- m-gate GEMM (A = rh): R14-proven 3 blk/CU structure ----------------
// tile 128x128, 4 waves, 48KB = A single (16K) + B double (2x16K), (256,3).
__global__ __launch_bounds__(256, 3) void k_m_gemm(
    uint8_t* __restrict__ ws, const float* __restrict__ bm, u32* __restrict__ dout) {
  int bx = blockIdx.x;
  int L = (bx & 7) * 256 + (bx >> 3);   // nwg=2048
  int vo = L & 63, mb = L >> 6;

  const uint8_t* wt_b = ws + OFF_WT + (size_t)2 * 27 * 32768;
  const uint8_t* xb_b = ws + OFF_XB;
  const uint8_t* lb_b = ws + OFF_LB + (size_t)2 * 8192 * 2048;
  const uint8_t* as_b = ws + OFF_RH;

  // LDS: [0,16K) A single-buffer; [16K,32K) B0; [32K,48K) B1
  __shared__ __align__(1024) uint8_t lds[49152];

  const int tid = threadIdx.x;
  const int w = tid >> 6;
  const int l = tid & 63;
  const int lrow = l >> 3;
  const int co = (((l & 7) ^ lrow) << 4);
  const int wm = (w >> 1) * 64;
  const int wn = (w & 1) * 64;
  const int lr16 = l & 15;
  const int lk = l >> 4;

  f32x4 acc[4][4];
#pragma unroll
  for (int m = 0; m < 4; ++m)
#pragma unroll
    for (int n = 0; n < 4; ++n) acc[m][n] = (f32x4){0.f, 0.f, 0.f, 0.f};

  const uint8_t* aA_x = xb_b + ((size_t)(mb * 128 + w * 32 + lrow)) * 2048 + co;
  const uint8_t* aA_t = as_b + ((size_t)(mb * 128 + w * 32 + lrow)) * 16384 + co;
  const uint8_t* aB_x = lb_b + ((size_t)(w * 32 + lrow)) * 131072 + (size_t)vo * 2048 + co;
  const uint8_t* aB_t = wt_b + ((size_t)(w * 32 + lrow)) * 256 + co;

  const int d = vo >> 4, e = (vo >> 2) & 3, f = vo & 3;
  auto validT = [&](int t) {
    int p3 = t / 9 - 1, q3 = (t / 3) % 3 - 1, s3 = t % 3 - 1;
    int dd = d + p3, ee = e + q3, ff = f + s3;
    return dd >= 0 && dd <= 3 && ee >= 0 && ee <= 3 && ff >= 0 && ff <= 3;
  };
  const int nd = 3 - (d == 0) - (d == 3);
  const int ne = 3 - (e == 0) - (e == 3);
  const int nf = 3 - (f == 0) - (f == 3);
  const int NP = 16 + 2 * nd * ne * nf;

  int s_kt = 0;
  int s_t = 0, s_ih = 0;
  while (!validT(s_t)) ++s_t;

  auto stage_next = [&](int bbuf) {
    uint8_t* Ad = lds + w * 4096;
    uint8_t* Bd = lds + 16384 + bbuf * 16384 + w * 4096;
    if (s_kt < 16) {
      int kt = s_kt;
#pragma unroll
      for (int pp = 0; pp < 4; ++pp)
        gload16(aA_x + (size_t)kt * 128 + pp * 16384, Ad + pp * 1024);
#pragma unroll
      for (int pp = 0; pp < 4; ++pp)
        gload16(aB_x + (size_t)kt * 128 + (size_t)pp * 1048576, Bd + pp * 1024);
      ++s_kt;
    } else {
      int t = s_t, ih = s_ih;
      int dd = d + t / 9 - 1, ee = e + (t / 3) % 3 - 1, ff = f + t % 3 - 1;
      int vi = dd * 16 + ee * 4 + ff;
#pragma unroll
      for (int pp = 0; pp < 4; ++pp)
        gload16(aA_t + (size_t)vi * 256 + ih * 128 + pp * 131072, Ad + pp * 1024);
#pragma unroll
      for (int pp = 0; pp < 4; ++pp)
        gload16(aB_t + (size_t)t * 32768 + ih * 128 + pp * 2048, Bd + pp * 1024);
      s_ih ^= 1;
      if (!s_ih) { do { ++s_t; } while (s_t < 27 && !validT(s_t)); }
    }
  };

  stage_next(0);
  __syncthreads();
  for (int p = 0; p < NP; ++p) {
    int cur = p & 1;
    const u16* At = (const u16*)lds;
    const u16* Bt = (const u16*)(lds + 16384 + cur * 16384);
    bf16x8 af[4][2], bfr[4][2];
#pragma unroll
    for (int m = 0; m < 4; ++m)
#pragma unroll
      for (int ks = 0; ks < 2; ++ks) {
        int row = wm + m * 16 + lr16;
        int c = ks * 4 + lk;
        af[m][ks] = *(const bf16x8*)&At[row * 64 + ((c ^ (row & 7)) * 8)];
      }
#pragma unroll
    for (int n = 0; n < 4; ++n)
#pragma unroll
      for (int ks = 0; ks < 2; ++ks) {
        int row = wn + n * 16 + lr16;
        int c = ks * 4 + lk;
        bfr[n][ks] = *(const bf16x8*)&Bt[row * 64 + ((c ^ (row & 7)) * 8)];
      }
    __syncthreads();
    if (p + 1 < NP) stage_next(cur ^ 1);
#pragma unroll
    for (int ks = 0; ks < 2; ++ks)
#pragma unroll
      for (int m = 0; m < 4; ++m)
#pragma unroll
        for (int n = 0; n < 4; ++n)
          acc[m][n] = __builtin_amdgcn_mfma_f32_16x16x32_bf16(af[m][ks], bfr[n][ks], acc[m][n], 0, 0, 0);
    __syncthreads();
  }

#pragma unroll
  for (int n = 0; n < 4; ++n) {
    int oc = wn + n * 16 + lr16;
    float bv = bm[oc * 64 + vo];
#pragma unroll
    for (int m = 0; m < 4; ++m) {
#pragma unroll
      for (int j = 0; j < 4; ++j) {
        int brow = mb * 128 + wm + m * 16 + lk * 4 + j;
        size_t pidx = (size_t)brow * 8192 + (size_t)vo * 128 + oc;
        float pre = acc[m][n][j] + bv;
        pre = fminf(fmaxf(pre, -30.f), 30.f);
        float e2 = __expf(-2.f * pre);
        float th = (1.f - e2) / (1.f + e2);     // tanh
        u32 old = dout[pidx];
        dout[pidx] = (old & 0xFFFFu) | (((u32)f2bf(th)) << 16);  // mem in hi16
      }
    }
  }
}

// ---------------- final combine: out[b][oc][vo] = (1-z)h + z*mem ----------------
__global__ __launch_bounds__(256) void k_combine(const float* __restrict__ h, u32* __restrict__ dout) {
  __shared__ u32 tile[64 * 129];
  int b = blockIdx.x;
  const u32* db = dout + (size_t)b * 8192;
  for (int i = threadIdx.x; i < 8192; i += 256) {
    int vo = i >> 7, oc = i & 127;
    tile[vo * 129 + oc] = db[i];
  }
  __syncthreads();
  float* ob = (float*)dout + (size_t)b * 8192;
  const float* hb = h + (size_t)b * 8192;
  for (int o = threadIdx.x; o < 8192; o += 256) {
    int oc = o >> 6, vo = o & 63;
    u32 pk = tile[vo * 129 + oc];
    float z = bf2f((u16)(pk & 0xFFFFu));
    float mem = bf2f((u16)(pk >> 16));
    ob[o] = (1.f - z) * hb[o] + z * mem;
  }
}

extern "C" void kernel_launch(void* const* d_in, const int* in_sizes, int n_in,
                              void* d_out, int out_size, void* d_ws, size_t ws_size,
                              hipStream_t stream) {
  const float* x  = (const float*)d_in[0];
  const float* h  = (const float*)d_in[1];
  const float* Wz = (const float*)d_in[2];
  const float* Wr = (const float*)d_in[3];
  const float* Wm = (const float*)d_in[4];
  const float* bz = (const float*)d_in[5];
  const float* br = (const float*)d_in[6];
  const float* bm = (const float*)d_in[7];
  const float* Lz = (const float*)d_in[8];
  const float* Lr = (const float*)d_in[9];
  const float* Lm = (const float*)d_in[10];
  uint8_t* ws = (uint8_t*)d_ws;
  u32* dout = (u32*)d_out;

  k_cvt<<<2048, 256, 0, stream>>>(x, Wz, Wr, Wm, Lz, Lr, Lm, ws);
  k_ht<<<4096, 256, 0, stream>>>(h, ws);
  // fused z+r: 32 mb * 64 vo = 2048 blocks, 512 thr, XCD-chunked, 3 blk/CU
  k_zr_gemm<<<2048, 512, 0, stream>>>(ws, bz, br, dout);
  // m: 2048 blocks, 256 thr, R14 structure
  k_m_gemm<<<2048, 256, 0, stream>>>(ws, bm, dout);
  k_combine<<<4096, 256, 0, stream>>>(h, dout);
}

// Round 18
// 913.239 us; speedup vs baseline: 7.9368x; 7.9368x over previous
//
#include <hip/hip_runtime.h>
#include <cstdint>

typedef __attribute__((ext_vector_type(8))) short bf16x8;
typedef __attribute__((ext_vector_type(4))) float f32x4;
typedef unsigned short u16;
typedef unsigned int u32;

// ---- problem sizes ----
// B=4096, Nh=128, vox=64 (4x4x4), Kx=1024
// ---- ws layout (bytes), all 16B aligned ----
static const size_t OFF_WT = 0;          // bf16 [3][27][128 oc][128 ic] = 2,654,208
static const size_t OFF_XB = 2654464;    // bf16 [4096][1024]            = 8,388,608
static const size_t OFF_LB = 11043072;   // bf16 [3][8192 (oc*64+vo)][1024] = 50,331,648
static const size_t OFF_HT = 61374720;   // bf16 [4096][64 vox][128 ic]  = 67,108,864
static const size_t OFF_RH = 128483584;  // bf16 [4096][64 vox][128 ic]  = 67,108,864
// total = 195,592,448 bytes required in d_ws

__device__ __forceinline__ u16 f2bf(float x) {
  union { float f; u32 u; } v; v.f = x;
  u32 r = (v.u + 0x7FFFu + ((v.u >> 16) & 1u)) >> 16;
  return (u16)r;
}
__device__ __forceinline__ float bf2f(u16 x) {
  union { u32 u; float f; } v; v.u = ((u32)x) << 16; return v.f;
}

__device__ __forceinline__ void gload16(const void* g, void* l) {
  __builtin_amdgcn_global_load_lds(
      (const __attribute__((address_space(1))) uint32_t*)g,
      (__attribute__((address_space(3))) uint32_t*)l, 16, 0, 0);
}

// ---------------- conversions: W->wt (transposed), x->xb, L->Lb ----------------
__global__ __launch_bounds__(256) void k_cvt(
    const float* __restrict__ x,
    const float* __restrict__ Wz, const float* __restrict__ Wr, const float* __restrict__ Wm,
    const float* __restrict__ Lz, const float* __restrict__ Lr, const float* __restrict__ Lm,
    uint8_t* __restrict__ ws) {
  u16* wt = (u16*)(ws + OFF_WT);
  u16* xb = (u16*)(ws + OFF_XB);
  u16* lb = (u16*)(ws + OFF_LB);
  const long NWT = 3L * 27 * 128 * 128;   // 1,327,104
  const long NX  = 4096L * 1024;          // 4,194,304
  const long NL  = 3L * 8192 * 1024;      // 25,165,824
  const long total = NWT + NX + NL;
  for (long i = (long)blockIdx.x * blockDim.x + threadIdx.x; i < total;
       i += (long)gridDim.x * blockDim.x) {
    if (i < NWT) {
      long g = i / (27L * 16384);
      long r = i % (27L * 16384);
      long t = r / 16384;
      long oc = (r / 128) % 128;
      long ic = r % 128;
      const float* W = (g == 0) ? Wz : ((g == 1) ? Wr : Wm);
      wt[i] = f2bf(W[(oc * 128 + ic) * 27 + t]);
    } else if (i < NWT + NX) {
      long j = i - NWT;
      xb[j] = f2bf(x[j]);
    } else {
      long j = i - NWT - NX;
      long g = j / (8192L * 1024);
      long r = j % (8192L * 1024);
      const float* L = (g == 0) ? Lz : ((g == 1) ? Lr : Lm);
      lb[j] = f2bf(L[r]);
    }
  }
}

// ---------------- h [b][ic][vox] fp32 -> ht [b][vox][ic] bf16 ----------------
__global__ __launch_bounds__(256) void k_ht(const float* __restrict__ h, uint8_t* __restrict__ ws) {
  __shared__ float tile[128 * 65];
  int b = blockIdx.x;
  const float* hb = h + (size_t)b * 8192;
  u16* ht = (u16*)(ws + OFF_HT) + (size_t)b * 8192;
  for (int i = threadIdx.x; i < 8192; i += 256) {
    int ic = i >> 6, vo = i & 63;
    tile[ic * 65 + vo] = hb[i];
  }
  __syncthreads();
  for (int i = threadIdx.x; i < 8192; i += 256) {
    int vo = i >> 7, ic = i & 127;
    ht[i] = f2bf(tile[ic * 65 + vo]);
  }
}

// ---------------- main per-voxel GEMM: conv taps + folded projection ----------------
// MODE 0: gates z(g=0)/r(g=1), A = ht.  MODE 1: gate m, A = rh (mem -> hi16).
// Block tile 128(M=batch) x 128(N=oc), BK=64; 512 thr = 8 waves (2M x 4N),
// each wave 64x32 -> per-wave regs ~104 unified (acc 16 + af 32 + bfr 16 +
// addr) -> 4 waves/SIMD (cap 128 via (512,4)), 16 waves/CU (R17 lesson: the
// occupancy dial is register-pool-bound; smaller wave tile is the only way up).
// 32 KB LDS single buffer: per panel, ds_read ALL frags into regs ->
// __syncthreads -> stage p+1 into the SAME buffer (safe: p is in regs) ->
// 16 MFMA/wave -> __syncthreads (drains vmcnt).
// Staging: global_load_lds width=16, linear LDS dest, XOR-swizzle on the
// per-lane GLOBAL source chunk; reads use At[row][c^(row&7)]; staged base
// rows are multiples of 8 so row&7 == staging lane's lrow (swizzle invariant).
// Grid: XCD-chunked bijective swizzle; order g fast, vo mid, mb slow.
// NOTE (R12): final combine CANNOT fuse into MODE1 (dout aliasing across blocks).
template <int MODE>
__global__ __launch_bounds__(512, 4) void k_conv_gemm(
    uint8_t* __restrict__ ws,
    const float* __restrict__ bz, const float* __restrict__ br, const float* __restrict__ bm,
    u32* __restrict__ dout) {
  int bx = blockIdx.x;
  int g, vo, mb;
  if (MODE == 0) {
    int L = (bx & 7) * 512 + (bx >> 3);   // nwg=4096, cpx=512
    g = L & 1; vo = (L >> 1) & 63; mb = L >> 7;
  } else {
    int L = (bx & 7) * 256 + (bx >> 3);   // nwg=2048, cpx=256
    g = 2; vo = L & 63; mb = L >> 6;
  }

  const uint8_t* wt_b = ws + OFF_WT + (size_t)g * 27 * 32768;   // bytes
  const uint8_t* xb_b = ws + OFF_XB;
  const uint8_t* lb_b = ws + OFF_LB + (size_t)g * 8192 * 2048;
  const uint8_t* as_b = ws + ((MODE == 0) ? OFF_HT : OFF_RH);

  // LDS: [0,16K) A; [16K,32K) B — single buffer, overwritten each panel
  __shared__ __align__(1024) uint8_t lds[32768];

  const int tid = threadIdx.x;
  const int w = tid >> 6;         // wave 0..7
  const int l = tid & 63;
  const int lrow = l >> 3;        // 0..7
  const int co = (((l & 7) ^ lrow) << 4);  // pre-swizzled chunk byte offset (row-invariant)
  const int wm = (w >> 2) * 64;   // M base: 0 / 64
  const int wn = (w & 3) * 32;    // N base: 0,32,64,96
  const int lr16 = l & 15;
  const int lk = l >> 4;

  f32x4 acc[4][2];
#pragma unroll
  for (int m = 0; m < 4; ++m)
#pragma unroll
    for (int n = 0; n < 2; ++n) acc[m][n] = (f32x4){0.f, 0.f, 0.f, 0.f};

  // per-lane invariant source bases (each wave stages A rows [w*16,w*16+16),
  // B rows [w*16,w*16+16); load i covers rows +i*8)
  const uint8_t* aA_x = xb_b + ((size_t)(mb * 128 + w * 16 + lrow)) * 2048 + co;            // + kt*128 + i*16384
  const uint8_t* aA_t = as_b + ((size_t)(mb * 128 + w * 16 + lrow)) * 16384 + co;           // + vi*256 + ih*128 + i*131072
  const uint8_t* aB_x = lb_b + ((size_t)(w * 16 + lrow)) * 131072 + (size_t)vo * 2048 + co; // + kt*128 + i*1048576
  const uint8_t* aB_t = wt_b + ((size_t)(w * 16 + lrow)) * 256 + co;                        // + t*32768 + ih*128 + i*2048

  const int d = vo >> 4, e = (vo >> 2) & 3, f = vo & 3;
  auto validT = [&](int t) {
    int p3 = t / 9 - 1, q3 = (t / 3) % 3 - 1, s3 = t % 3 - 1;
    int dd = d + p3, ee = e + q3, ff = f + s3;
    return dd >= 0 && dd <= 3 && ee >= 0 && ee <= 3 && ff >= 0 && ff <= 3;
  };
  const int nd = 3 - (d == 0) - (d == 3);
  const int ne = 3 - (e == 0) - (e == 3);
  const int nf = 3 - (f == 0) - (f == 3);
  const int NP = 16 + 2 * nd * ne * nf;

  // panel iterator state (block-uniform)
  int s_kt = 0;            // next projection panel
  int s_t = 0, s_ih = 0;   // next tap panel
  while (!validT(s_t)) ++s_t;

  // stage panel into the single A+B buffer (2 A-loads + 2 B-loads per lane)
  auto stage_next = [&]() {
    uint8_t* Ad = lds + w * 2048;
    uint8_t* Bd = lds + 16384 + w * 2048;
    if (s_kt < 16) {
      int kt = s_kt;
#pragma unroll
      for (int i = 0; i < 2; ++i)
        gload16(aA_x + (size_t)kt * 128 + (size_t)i * 16384, Ad + i * 1024);
#pragma unroll
      for (int i = 0; i < 2; ++i)
        gload16(aB_x + (size_t)kt * 128 + (size_t)i * 1048576, Bd + i * 1024);
      ++s_kt;
    } else {
      int t = s_t, ih = s_ih;
      int dd = d + t / 9 - 1, ee = e + (t / 3) % 3 - 1, ff = f + t % 3 - 1;
      int vi = dd * 16 + ee * 4 + ff;
#pragma unroll
      for (int i = 0; i < 2; ++i)
        gload16(aA_t + (size_t)vi * 256 + ih * 128 + (size_t)i * 131072, Ad + i * 1024);
#pragma unroll
      for (int i = 0; i < 2; ++i)
        gload16(aB_t + (size_t)t * 32768 + ih * 128 + (size_t)i * 2048, Bd + i * 1024);
      s_ih ^= 1;
      if (!s_ih) { do { ++s_t; } while (s_t < 27 && !validT(s_t)); }
    }
  };

  // prologue: stage panel 0, drain
  stage_next();
  __syncthreads();
  for (int p = 0; p < NP; ++p) {
    const u16* At = (const u16*)lds;                 // 128 rows x 64
    const u16* Bt = (const u16*)(lds + 16384);       // 128 rows x 64
    // ---- read ALL fragments into registers first ----
    bf16x8 af[4][2], bfr[2][2];
#pragma unroll
    for (int m = 0; m < 4; ++m)
#pragma unroll
      for (int ks = 0; ks < 2; ++ks) {
        int row = wm + m * 16 + lr16;
        int c = ks * 4 + lk;
        af[m][ks] = *(const bf16x8*)&At[row * 64 + ((c ^ (row & 7)) * 8)];
      }
#pragma unroll
    for (int n = 0; n < 2; ++n)
#pragma unroll
      for (int ks = 0; ks < 2; ++ks) {
        int row = wn + n * 16 + lr16;
        int c = ks * 4 + lk;
        bfr[n][ks] = *(const bf16x8*)&Bt[row * 64 + ((c ^ (row & 7)) * 8)];
      }
    __syncthreads();   // all waves consumed panel p from LDS (buffer free)
    if (p + 1 < NP) stage_next();   // loads fly under the MFMAs
    // ---- MFMA on registers ----
#pragma unroll
    for (int ks = 0; ks < 2; ++ks)
#pragma unroll
      for (int m = 0; m < 4; ++m)
#pragma unroll
        for (int n = 0; n < 2; ++n)
          acc[m][n] = __builtin_amdgcn_mfma_f32_16x16x32_bf16(af[m][ks], bfr[n][ks], acc[m][n], 0, 0, 0);
    __syncthreads();   // drains vmcnt -> panel p+1 resident before next reads
  }

  // --- epilogue ---
  const float* bias = (MODE == 0) ? ((g == 0) ? bz : br) : bm;
  const u16* htp = (const u16*)(ws + OFF_HT);
  u16* rhp = (u16*)(ws + OFF_RH);
#pragma unroll
  for (int n = 0; n < 2; ++n) {
    int oc = wn + n * 16 + lr16;
    float bv = bias[oc * 64 + vo];
#pragma unroll
    for (int m = 0; m < 4; ++m) {
#pragma unroll
      for (int j = 0; j < 4; ++j) {
        int brow = mb * 128 + wm + m * 16 + lk * 4 + j;  // batch index
        size_t pidx = (size_t)brow * 8192 + (size_t)vo * 128 + oc;
        float pre = acc[m][n][j] + bv;
        pre = fminf(fmaxf(pre, -30.f), 30.f);
        if (MODE == 0) {
          float sg = 1.f / (1.f + __expf(-pre));
          if (g == 0) {
            dout[pidx] = (u32)f2bf(sg);           // z in lo16 (hi cleared)
          } else {
            float hv = bf2f(htp[pidx]);
            rhp[pidx] = f2bf(sg * hv);            // r * h
          }
        } else {
          float e2 = __expf(-2.f * pre);
          float th = (1.f - e2) / (1.f + e2);     // tanh
          u32 old = dout[pidx];
          dout[pidx] = (old & 0xFFFFu) | (((u32)f2bf(th)) << 16);  // mem in hi16
        }
      }
    }
  }
}

// ---------------- final combine: out[b][oc][vo] = (1-z)h + z*mem ----------------
__global__ __launch_bounds__(256) void k_combine(const float* __restrict__ h, u32* __restrict__ dout) {
  __shared__ u32 tile[64 * 129];
  int b = blockIdx.x;
  const u32* db = dout + (size_t)b * 8192;
  for (int i = threadIdx.x; i < 8192; i += 256) {
    int vo = i >> 7, oc = i & 127;
    tile[vo * 129 + oc] = db[i];
  }
  __syncthreads();
  float* ob = (float*)dout + (size_t)b * 8192;
  const float* hb = h + (size_t)b * 8192;
  for (int o = threadIdx.x; o < 8192; o += 256) {
    int oc = o >> 6, vo = o & 63;
    u32 pk = tile[vo * 129 + oc];
    float z = bf2f((u16)(pk & 0xFFFFu));
    float mem = bf2f((u16)(pk >> 16));
    ob[o] = (1.f - z) * hb[o] + z * mem;
  }
}

extern "C" void kernel_launch(void* const* d_in, const int* in_sizes, int n_in,
                              void* d_out, int out_size, void* d_ws, size_t ws_size,
                              hipStream_t stream) {
  const float* x  = (const float*)d_in[0];
  const float* h  = (const float*)d_in[1];
  const float* Wz = (const float*)d_in[2];
  const float* Wr = (const float*)d_in[3];
  const float* Wm = (const float*)d_in[4];
  const float* bz = (const float*)d_in[5];
  const float* br = (const float*)d_in[6];
  const float* bm = (const float*)d_in[7];
  const float* Lz = (const float*)d_in[8];
  const float* Lr = (const float*)d_in[9];
  const float* Lm = (const float*)d_in[10];
  uint8_t* ws = (uint8_t*)d_ws;
  u32* dout = (u32*)d_out;

  k_cvt<<<2048, 256, 0, stream>>>(x, Wz, Wr, Wm, Lz, Lr, Lm, ws);
  k_ht<<<4096, 256, 0, stream>>>(h, ws);
  // z and r: 4096 blocks x 512 thr, XCD-chunked; order g fast, vo mid, mb slow
  k_conv_gemm<0><<<4096, 512, 0, stream>>>(ws, bz, br, bm, dout);
  // m: 2048 blocks x 512 thr, XCD-chunked
  k_conv_gemm<1><<<2048, 512, 0, stream>>>(ws, bz, br, bm, dout);
  k_combine<<<4096, 256, 0, stream>>>(h, dout);
}

// Round 19
// 878.295 us; speedup vs baseline: 8.2525x; 1.0398x over previous
//
#include <hip/hip_runtime.h>
#include <cstdint>

typedef __attribute__((ext_vector_type(8))) short bf16x8;
typedef __attribute__((ext_vector_type(4))) float f32x4;
typedef unsigned short u16;
typedef unsigned int u32;

// ---- problem sizes ----
// B=4096, Nh=128, vox=64 (4x4x4), Kx=1024
// ---- ws layout (bytes), all 16B aligned ----
static const size_t OFF_WT = 0;          // bf16 [3][27][128 oc][128 ic] = 2,654,208
static const size_t OFF_XB = 2654464;    // bf16 [4096][1024]            = 8,388,608
static const size_t OFF_LB = 11043072;   // bf16 [3][8192 (oc*64+vo)][1024] = 50,331,648
static const size_t OFF_HT = 61374720;   // bf16 [4096][64 vox][128 ic]  = 67,108,864
static const size_t OFF_RH = 128483584;  // bf16 [4096][64 vox][128 ic]  = 67,108,864
// total = 195,592,448 bytes required in d_ws

__device__ __forceinline__ u16 f2bf(float x) {
  union { float f; u32 u; } v; v.f = x;
  u32 r = (v.u + 0x7FFFu + ((v.u >> 16) & 1u)) >> 16;
  return (u16)r;
}
__device__ __forceinline__ float bf2f(u16 x) {
  union { u32 u; float f; } v; v.u = ((u32)x) << 16; return v.f;
}

__device__ __forceinline__ void gload16(const void* g, void* l) {
  __builtin_amdgcn_global_load_lds(
      (const __attribute__((address_space(1))) uint32_t*)g,
      (__attribute__((address_space(3))) uint32_t*)l, 16, 0, 0);
}

// ---------------- conversions: W->wt (transposed), x->xb, L->Lb ----------------
__global__ __launch_bounds__(256) void k_cvt(
    const float* __restrict__ x,
    const float* __restrict__ Wz, const float* __restrict__ Wr, const float* __restrict__ Wm,
    const float* __restrict__ Lz, const float* __restrict__ Lr, const float* __restrict__ Lm,
    uint8_t* __restrict__ ws) {
  u16* wt = (u16*)(ws + OFF_WT);
  u16* xb = (u16*)(ws + OFF_XB);
  u16* lb = (u16*)(ws + OFF_LB);
  const long NWT = 3L * 27 * 128 * 128;   // 1,327,104
  const long NX  = 4096L * 1024;          // 4,194,304
  const long NL  = 3L * 8192 * 1024;      // 25,165,824
  const long total = NWT + NX + NL;
  for (long i = (long)blockIdx.x * blockDim.x + threadIdx.x; i < total;
       i += (long)gridDim.x * blockDim.x) {
    if (i < NWT) {
      long g = i / (27L * 16384);
      long r = i % (27L * 16384);
      long t = r / 16384;
      long oc = (r / 128) % 128;
      long ic = r % 128;
      const float* W = (g == 0) ? Wz : ((g == 1) ? Wr : Wm);
      wt[i] = f2bf(W[(oc * 128 + ic) * 27 + t]);
    } else if (i < NWT + NX) {
      long j = i - NWT;
      xb[j] = f2bf(x[j]);
    } else {
      long j = i - NWT - NX;
      long g = j / (8192L * 1024);
      long r = j % (8192L * 1024);
      const float* L = (g == 0) ? Lz : ((g == 1) ? Lr : Lm);
      lb[j] = f2bf(L[r]);
    }
  }
}

// ---------------- h [b][ic][vox] fp32 -> ht [b][vox][ic] bf16 ----------------
__global__ __launch_bounds__(256) void k_ht(const float* __restrict__ h, uint8_t* __restrict__ ws) {
  __shared__ float tile[128 * 65];
  int b = blockIdx.x;
  const float* hb = h + (size_t)b * 8192;
  u16* ht = (u16*)(ws + OFF_HT) + (size_t)b * 8192;
  for (int i = threadIdx.x; i < 8192; i += 256) {
    int ic = i >> 6, vo = i & 63;
    tile[ic * 65 + vo] = hb[i];
  }
  __syncthreads();
  for (int i = threadIdx.x; i < 8192; i += 256) {
    int vo = i >> 7, ic = i & 127;
    ht[i] = f2bf(tile[ic * 65 + vo]);
  }
}

// ---------------- main per-voxel GEMM: conv taps + folded projection ----------------
// MODE 0: gates z(g=0)/r(g=1), A = ht.  MODE 1: gate m, A = rh (mem -> hi16).
// tile 128(M=batch) x 128(N=oc), BK=64, 4 waves each 64x64.
// 3 blocks/CU schedule (measured optimum of the register-feasibility arc:
// 144-reg working set admits exactly 3 waves/SIMD; (256,4)/(256,5) caps spill
// [R15/R16], 8-wave 64x32 split loses to barrier overhead [R18]).
// 48 KB LDS = A single-buffer (16KB) + B double-buffer (2x16KB). Per panel:
// ds_read all 16 frags into regs -> __syncthreads -> stage panel p+1
// (A overwrite safe: all waves consumed A(p)) -> 32 MFMA -> __syncthreads
// (drains vmcnt). Staging via global_load_lds width=16, linear LDS dest,
// XOR-swizzle on per-lane GLOBAL source chunk; reads use At[row][c^(row&7)].
// Grid: XCD-chunked bijective swizzle; order g fast, vo mid, mb slow.
// NOTE (R12): final combine CANNOT fuse into MODE1 (dout aliasing across blocks).
template <int MODE>
__global__ __launch_bounds__(256, 3) void k_conv_gemm(
    uint8_t* __restrict__ ws,
    const float* __restrict__ bz, const float* __restrict__ br, const float* __restrict__ bm,
    u32* __restrict__ dout) {
  int bx = blockIdx.x;
  int g, vo, mb;
  if (MODE == 0) {
    int L = (bx & 7) * 512 + (bx >> 3);   // nwg=4096, cpx=512
    g = L & 1; vo = (L >> 1) & 63; mb = L >> 7;
  } else {
    int L = (bx & 7) * 256 + (bx >> 3);   // nwg=2048, cpx=256
    g = 2; vo = L & 63; mb = L >> 6;
  }

  const uint8_t* wt_b = ws + OFF_WT + (size_t)g * 27 * 32768;   // bytes
  const uint8_t* xb_b = ws + OFF_XB;
  const uint8_t* lb_b = ws + OFF_LB + (size_t)g * 8192 * 2048;
  const uint8_t* as_b = ws + ((MODE == 0) ? OFF_HT : OFF_RH);

  // LDS: [0,16K) A single-buffer; [16K,32K) B0; [32K,48K) B1
  __shared__ __align__(1024) uint8_t lds[49152];

  const int tid = threadIdx.x;
  const int w = tid >> 6;         // wave
  const int l = tid & 63;
  const int lrow = l >> 3;        // row-within-8 handled by this lane
  const int co = (((l & 7) ^ lrow) << 4);  // pre-swizzled chunk byte offset (row-invariant)
  const int wm = (w >> 1) * 64;   // M base in tile
  const int wn = (w & 1) * 64;    // N base in tile
  const int lr16 = l & 15;
  const int lk = l >> 4;

  f32x4 acc[4][4];
#pragma unroll
  for (int m = 0; m < 4; ++m)
#pragma unroll
    for (int n = 0; n < 4; ++n) acc[m][n] = (f32x4){0.f, 0.f, 0.f, 0.f};

  // per-lane invariant source bases
  const uint8_t* aA_x = xb_b + ((size_t)(mb * 128 + w * 32 + lrow)) * 2048 + co;            // + kt*128 + pp*16384
  const uint8_t* aA_t = as_b + ((size_t)(mb * 128 + w * 32 + lrow)) * 16384 + co;           // + vi*256 + ih*128 + pp*131072
  const uint8_t* aB_x = lb_b + ((size_t)(w * 32 + lrow)) * 131072 + (size_t)vo * 2048 + co; // + kt*128 + pp*1048576
  const uint8_t* aB_t = wt_b + ((size_t)(w * 32 + lrow)) * 256 + co;                        // + t*32768 + ih*128 + pp*2048

  const int d = vo >> 4, e = (vo >> 2) & 3, f = vo & 3;
  auto validT = [&](int t) {
    int p3 = t / 9 - 1, q3 = (t / 3) % 3 - 1, s3 = t % 3 - 1;
    int dd = d + p3, ee = e + q3, ff = f + s3;
    return dd >= 0 && dd <= 3 && ee >= 0 && ee <= 3 && ff >= 0 && ff <= 3;
  };
  const int nd = 3 - (d == 0) - (d == 3);
  const int ne = 3 - (e == 0) - (e == 3);
  const int nf = 3 - (f == 0) - (f == 3);
  const int NP = 16 + 2 * nd * ne * nf;

  // panel iterator state (block-uniform)
  int s_kt = 0;            // next projection panel
  int s_t = 0, s_ih = 0;   // next tap panel
  while (!validT(s_t)) ++s_t;

  // stage panel into A-buffer + B[bbuf]
  auto stage_next = [&](int bbuf) {
    uint8_t* Ad = lds + w * 4096;
    uint8_t* Bd = lds + 16384 + bbuf * 16384 + w * 4096;
    if (s_kt < 16) {
      int kt = s_kt;
#pragma unroll
      for (int pp = 0; pp < 4; ++pp)
        gload16(aA_x + (size_t)kt * 128 + pp * 16384, Ad + pp * 1024);
#pragma unroll
      for (int pp = 0; pp < 4; ++pp)
        gload16(aB_x + (size_t)kt * 128 + (size_t)pp * 1048576, Bd + pp * 1024);
      ++s_kt;
    } else {
      int t = s_t, ih = s_ih;
      int dd = d + t / 9 - 1, ee = e + (t / 3) % 3 - 1, ff = f + t % 3 - 1;
      int vi = dd * 16 + ee * 4 + ff;
#pragma unroll
      for (int pp = 0; pp < 4; ++pp)
        gload16(aA_t + (size_t)vi * 256 + ih * 128 + pp * 131072, Ad + pp * 1024);
#pragma unroll
      for (int pp = 0; pp < 4; ++pp)
        gload16(aB_t + (size_t)t * 32768 + ih * 128 + pp * 2048, Bd + pp * 1024);
      s_ih ^= 1;
      if (!s_ih) { do { ++s_t; } while (s_t < 27 && !validT(s_t)); }
    }
  };

  // prologue: stage panel 0 into A + B0, drain
  stage_next(0);
  __syncthreads();
  for (int p = 0; p < NP; ++p) {
    int cur = p & 1;
    const u16* At = (const u16*)lds;                              // 128 rows x 64
    const u16* Bt = (const u16*)(lds + 16384 + cur * 16384);      // 128 rows x 64
    // ---- read ALL fragments into registers first ----
    bf16x8 af[4][2], bfr[4][2];
#pragma unroll
    for (int m = 0; m < 4; ++m)
#pragma unroll
      for (int ks = 0; ks < 2; ++ks) {
        int row = wm + m * 16 + lr16;
        int c = ks * 4 + lk;
        af[m][ks] = *(const bf16x8*)&At[row * 64 + ((c ^ (row & 7)) * 8)];
      }
#pragma unroll
    for (int n = 0; n < 4; ++n)
#pragma unroll
      for (int ks = 0; ks < 2; ++ks) {
        int row = wn + n * 16 + lr16;
        int c = ks * 4 + lk;
        bfr[n][ks] = *(const bf16x8*)&Bt[row * 64 + ((c ^ (row & 7)) * 8)];
      }
    __syncthreads();   // all waves consumed panel p from LDS (A free to overwrite)
    if (p + 1 < NP) stage_next(cur ^ 1);   // loads fly under the MFMAs
    // ---- MFMA on registers ----
#pragma unroll
    for (int ks = 0; ks < 2; ++ks)
#pragma unroll
      for (int m = 0; m < 4; ++m)
#pragma unroll
        for (int n = 0; n < 4; ++n)
          acc[m][n] = __builtin_amdgcn_mfma_f32_16x16x32_bf16(af[m][ks], bfr[n][ks], acc[m][n], 0, 0, 0);
    __syncthreads();   // drains vmcnt -> panel p+1 resident before next reads
  }

  // --- epilogue ---
  const float* bias = (MODE == 0) ? ((g == 0) ? bz : br) : bm;
  const u16* htp = (const u16*)(ws + OFF_HT);
  u16* rhp = (u16*)(ws + OFF_RH);
#pragma unroll
  for (int n = 0; n < 4; ++n) {
    int oc = wn + n * 16 + lr16;
    float bv = bias[oc * 64 + vo];
#pragma unroll
    for (int m = 0; m < 4; ++m) {
#pragma unroll
      for (int j = 0; j < 4; ++j) {
        int brow = mb * 128 + wm + m * 16 + lk * 4 + j;  // batch index
        size_t pidx = (size_t)brow * 8192 + (size_t)vo * 128 + oc;
        float pre = acc[m][n][j] + bv;
        pre = fminf(fmaxf(pre, -30.f), 30.f);
        if (MODE == 0) {
          float sg = 1.f / (1.f + __expf(-pre));
          if (g == 0) {
            dout[pidx] = (u32)f2bf(sg);           // z in lo16 (hi cleared)
          } else {
            float hv = bf2f(htp[pidx]);
            rhp[pidx] = f2bf(sg * hv);            // r * h
          }
        } else {
          float e2 = __expf(-2.f * pre);
          float th = (1.f - e2) / (1.f + e2);     // tanh
          u32 old = dout[pidx];
          dout[pidx] = (old & 0xFFFFu) | (((u32)f2bf(th)) << 16);  // mem in hi16
        }
      }
    }
  }
}

// ---------------- final combine: out[b][oc][vo] = (1-z)h + z*mem ----------------
__global__ __launch_bounds__(256) void k_combine(const float* __restrict__ h, u32* __restrict__ dout) {
  __shared__ u32 tile[64 * 129];
  int b = blockIdx.x;
  const u32* db = dout + (size_t)b * 8192;
  for (int i = threadIdx.x; i < 8192; i += 256) {
    int vo = i >> 7, oc = i & 127;
    tile[vo * 129 + oc] = db[i];
  }
  __syncthreads();
  float* ob = (float*)dout + (size_t)b * 8192;
  const float* hb = h + (size_t)b * 8192;
  for (int o = threadIdx.x; o < 8192; o += 256) {
    int oc = o >> 6, vo = o & 63;
    u32 pk = tile[vo * 129 + oc];
    float z = bf2f((u16)(pk & 0xFFFFu));
    float mem = bf2f((u16)(pk >> 16));
    ob[o] = (1.f - z) * hb[o] + z * mem;
  }
}

extern "C" void kernel_launch(void* const* d_in, const int* in_sizes, int n_in,
                              void* d_out, int out_size, void* d_ws, size_t ws_size,
                              hipStream_t stream) {
  const float* x  = (const float*)d_in[0];
  const float* h  = (const float*)d_in[1];
  const float* Wz = (const float*)d_in[2];
  const float* Wr = (const float*)d_in[3];
  const float* Wm = (const float*)d_in[4];
  const float* bz = (const float*)d_in[5];
  const float* br = (const float*)d_in[6];
  const float* bm = (const float*)d_in[7];
  const float* Lz = (const float*)d_in[8];
  const float* Lr = (const float*)d_in[9];
  const float* Lm = (const float*)d_in[10];
  uint8_t* ws = (uint8_t*)d_ws;
  u32* dout = (u32*)d_out;

  k_cvt<<<2048, 256, 0, stream>>>(x, Wz, Wr, Wm, Lz, Lr, Lm, ws);
  k_ht<<<4096, 256, 0, stream>>>(h, ws);
  // z and r: 4096 blocks, XCD-chunked; logical order g fast, vo mid, mb slow
  k_conv_gemm<0><<<4096, 256, 0, stream>>>(ws, bz, br, bm, dout);
  // m: 2048 blocks, XCD-chunked
  k_conv_gemm<1><<<2048, 256, 0, stream>>>(ws, bz, br, bm, dout);
  k_combine<<<4096, 256, 0, stream>>>(h, dout);
}